// Round 8
// baseline (9678.439 us; speedup 1.0000x reference)
//
#include <hip/hip_runtime.h>
#include <stdint.h>

#define T_LEN 4096
#define E_DIM 256
#define HH 256

typedef unsigned long long u64;

__device__ __forceinline__ float sigmoidf_(float x) {
    // 1/(1+e^-x) with approx rcp (rel err ~1e-7, fine vs 2% score threshold)
    return __builtin_amdgcn_rcpf(1.0f + __expf(-x));
}
// tanh via exp identity; exact saturation at +-1
__device__ __forceinline__ float tanh_fast(float x) {
    float e = __expf(2.0f * x);
    return 1.0f - 2.0f * __builtin_amdgcn_rcpf(e + 1.0f);
}

// DPP-based add of a permuted lane: pure VALU. CTRL: 0xB1 = quad_perm xor1,
// 0x4E = quad_perm xor2, 0x141 = ROW_HALF_MIRROR (l^7), 0x140 = ROW_MIRROR
// (l^15). After the 4-round chain ALL 16 lanes of each 16-row hold the row
// sum (mirrors are valid because values are quad/octet-uniform by then).
template <int CTRL>
__device__ __forceinline__ float dpp_add(float x) {
    int t = __builtin_amdgcn_update_dpp(0, __float_as_int(x), CTRL, 0xF, 0xF, true);
    return x + __int_as_float(t);
}

// R12: non-VMEM-draining workgroup barrier. __syncthreads() makes the
// compiler emit "s_waitcnt vmcnt(0) lgkmcnt(0)" before s_barrier, draining
// wave 7's in-flight HBM prefetch every step (~900cy — R11's regression).
// This sequence waits ONLY lgkmcnt (LDS visibility for producer ds_writes);
// raw s_barrier leaves VMEM in flight (HK 8-phase-proven, m201/m218);
// sched_barrier(0) stops the compiler hoisting post-barrier ds_reads above
// it (guide rule #18); "memory" clobber stops pre-barrier stores sinking.
__device__ __forceinline__ void block_sync_lds() {
    asm volatile("s_waitcnt lgkmcnt(0)" ::: "memory");
    __builtin_amdgcn_s_barrier();
    __builtin_amdgcn_sched_barrier(0);
}

// ---------------------------------------------------------------------------
// Kernel 1: embedding gather fused with input projection. (unchanged)
// ---------------------------------------------------------------------------
__global__ __launch_bounds__(256) void proj_kernel(
    const int* __restrict__ sent, const float* __restrict__ embed,
    const float* __restrict__ Wih_f, const float* __restrict__ bih_f, const float* __restrict__ bhh_f,
    const float* __restrict__ Wih_b, const float* __restrict__ bih_b, const float* __restrict__ bhh_b,
    float* __restrict__ gates_f, float* __restrict__ gates_b)
{
    __shared__ float4 xt[16][64];   // 16 timesteps x 256 floats
    const int tid = threadIdx.x;
    const int dir = blockIdx.y;
    const int t0  = blockIdx.x * 16;

    const float* Wih = dir ? Wih_b : Wih_f;
    const float* bih = dir ? bih_b : bih_f;
    const float* bhh = dir ? bhh_b : bhh_f;
    float* gates     = dir ? gates_b : gates_f;

    {   // gather 16 embedding rows into LDS (coalesced 16B/lane)
        int row = tid >> 4;
        int c   = tid & 15;
        const float4* src = (const float4*)(embed + (size_t)sent[t0 + row] * E_DIM);
        xt[row][c]      = src[c];
        xt[row][c + 16] = src[c + 16];
        xt[row][c + 32] = src[c + 32];
        xt[row][c + 48] = src[c + 48];
    }
    __syncthreads();

    float acc[4][16];
    #pragma unroll
    for (int ri = 0; ri < 4; ++ri)
        #pragma unroll
        for (int tt = 0; tt < 16; ++tt) acc[ri][tt] = 0.f;

    const float4* wrow0 = (const float4*)(Wih + (size_t)(0 * 256 + tid) * 256);
    const float4* wrow1 = (const float4*)(Wih + (size_t)(1 * 256 + tid) * 256);
    const float4* wrow2 = (const float4*)(Wih + (size_t)(2 * 256 + tid) * 256);
    const float4* wrow3 = (const float4*)(Wih + (size_t)(3 * 256 + tid) * 256);

    for (int k4 = 0; k4 < 64; ++k4) {
        float4 xv[16];
        #pragma unroll
        for (int tt = 0; tt < 16; ++tt) xv[tt] = xt[tt][k4];
        float4 w0 = wrow0[k4], w1 = wrow1[k4], w2 = wrow2[k4], w3 = wrow3[k4];
        #pragma unroll
        for (int tt = 0; tt < 16; ++tt) {
            acc[0][tt] += w0.x*xv[tt].x + w0.y*xv[tt].y + w0.z*xv[tt].z + w0.w*xv[tt].w;
            acc[1][tt] += w1.x*xv[tt].x + w1.y*xv[tt].y + w1.z*xv[tt].z + w1.w*xv[tt].w;
            acc[2][tt] += w2.x*xv[tt].x + w2.y*xv[tt].y + w2.z*xv[tt].z + w2.w*xv[tt].w;
            acc[3][tt] += w3.x*xv[tt].x + w3.y*xv[tt].y + w3.z*xv[tt].z + w3.w*xv[tt].w;
        }
    }

    #pragma unroll
    for (int ri = 0; ri < 4; ++ri) {
        int r = ri * 256 + tid;
        float b = bih[r] + bhh[r];
        #pragma unroll
        for (int tt = 0; tt < 16; ++tt)
            gates[(size_t)(t0 + tt) * 1024 + r] = acc[ri][tt] + b;
    }
}

// ---------------------------------------------------------------------------
// Kernel 2: BiLSTM recurrence. 64 blocks; blockIdx&7 in {0,1} work (dir=xcd).
// 8 blocks/dir x 32 hidden. Thread (j=tid>>4, s=tid&15).
// R12 = R11 structure + non-draining barrier (the single change).
// R11 post-mortem: __syncthreads emits vmcnt(0) before s_barrier, so wave
// 7's just-issued HBM prefetch was drained AT THE BARRIER every step
// (~900cy; lstm 4674->5570). block_sync_lds() keeps VMEM in flight.
// WAVE-LEVEL IO SEPARATION (R11): gin flows through wave 7 only (pollers
// are tid<256 = waves 0..3):
//   wave 7, end of step t: ds_write gin row t+1 (regs loaded at end of
//     t-1 -> register-dep waitcnt lands a full step after issue, HBM
//     latency fully shadowed), then issue global loads for row t+2.
//   activation lanes (s==14/15) ds_read gin from gin_lds[t&1] (written
//     step t-1, ordered by step t's barrier, double-buffered).
// Poller waves carry NO global loads -> their poll vmcnt(0) waits only on
// the single L2 atomic (+own store acks). Everything else R6-proven
// (poll mapping, AGPR-pinned w, 0-conflict b64 rotation, DPP reduce,
// ABA protocol -- barrier still orders poll-before-publish per block).
// ---------------------------------------------------------------------------
__global__ __launch_bounds__(512, 1) void lstm_kernel(
    const float* __restrict__ Whh_f, const float* __restrict__ Whh_b,
    const float* __restrict__ gates_f, const float* __restrict__ gates_b,
    const float* __restrict__ h0, const float* __restrict__ c0,
    float* __restrict__ h_out, u64* __restrict__ msg)
{
    const int xcd  = blockIdx.x & 7;
    const int slot = blockIdx.x >> 3;
    if (xcd > 1) return;               // filler blocks exit (before barriers)
    const int dir = xcd;
    const int g   = slot;              // 0..7, owns hidden [g*32, g*32+32)

    const int tid = threadIdx.x;
    const int jl  = tid >> 4;          // local hidden 0..31
    const int s   = tid & 15;          // k-slice 0..15 (16 floats each)
    const int j   = g * 32 + jl;       // global hidden index
    const int f   = (s + (s >> 3)) & 7;  // bank de-correlation rotation
    const int wv  = tid >> 6;          // wave 0..7
    const int lio = tid & 63;          // lane within wave (IO addressing)

    const float* Whh   = dir ? Whh_b : Whh_f;
    const float* gates = dir ? gates_b : gates_f;

    // w[gg*16 + i*2 + c] = Whh[gg*256+j][s*16 + ((3i+f)&7)*2 + c]
    // (stored in ds-visit order so the dot loop reads w linearly)
    float w[64];
    #pragma unroll
    for (int gg = 0; gg < 4; ++gg) {
        const float2* row2 = (const float2*)(Whh + (size_t)(gg * 256 + j) * 256 + s * 16);
        #pragma unroll
        for (int i = 0; i < 8; ++i) {
            float2 v = row2[(3 * i + f) & 7];
            w[gg * 16 + i * 2 + 0] = v.x;
            w[gg * 16 + i * 2 + 1] = v.y;
        }
    }
    // AGPR pin: forces w into the accumulator file; VALU reads a-regs as
    // FMA sources in place (gfx90a+), so no per-step accvgpr_read fills and
    // no rematerialization-from-memory.
    #pragma unroll
    for (int k = 0; k < 64; ++k)
        asm volatile("" : "+a"(w[k]));

    // per-i LDS byte offsets (t-invariant; 8 VGPRs, static-indexed)
    int off[8];
    #pragma unroll
    for (int i = 0; i < 8; ++i)
        off[i] = s * 64 + ((3 * i + f) & 7) * 8;

    __shared__ __align__(16) float h_lds[2][256];
    __shared__ __align__(16) float gin_lds[2][1024];   // gate*256 + j layout

    float c = 0.f;
    if (tid < 32) {
        int j0 = g * 32 + tid;
        float h = h0[dir * HH + j0];
        h_lds[0][j0] = h;
        u64 p = ((u64)1u << 32) | (u64)__float_as_uint(h);
        __hip_atomic_store(&msg[(0 * 2 + dir) * 256 + j0], p,
                           __ATOMIC_RELAXED, __HIP_MEMORY_SCOPE_AGENT);
    }
    if (s >= 14) c = c0[dir * HH + j];

    // IO prologue (wave 7): gin row for t=0 straight into gin_lds[0]
    // (step-0 barrier orders it for readers); row for t=1 held in regs.
    float4 q0 = {0,0,0,0}, q1 = {0,0,0,0}, q2 = {0,0,0,0}, q3 = {0,0,0,0};
    if (wv == 7) {
        const float4* r0 = (const float4*)(gates + (size_t)(dir ? (T_LEN - 1) : 0) * 1024);
        float4 a0 = r0[lio], a1 = r0[lio + 64], a2 = r0[lio + 128], a3 = r0[lio + 192];
        float4* gl0 = (float4*)&gin_lds[0][0];
        gl0[lio] = a0; gl0[lio + 64] = a1; gl0[lio + 128] = a2; gl0[lio + 192] = a3;
        const float4* r1 = (const float4*)(gates + (size_t)(dir ? (T_LEN - 2) : 1) * 1024);
        q0 = r1[lio]; q1 = r1[lio + 64]; q2 = r1[lio + 128]; q3 = r1[lio + 192];
    }

    for (int t = 0; t < T_LEN; ++t) {
        const int tf = dir ? (T_LEN - 1 - t) : t;

        // poll the 224 remote h values (waves 0..3; 1 slot per lane; these
        // waves have NO global loads outstanding -> vmcnt(0) is L2-cheap)
        if (tid < 256 && (tid >> 5) != g) {
            u64* sp = &msg[((t & 1) * 2 + dir) * 256 + tid];
            const unsigned want = (unsigned)(t + 1);
            u64 m;
            do {
                m = __hip_atomic_load(sp, __ATOMIC_RELAXED, __HIP_MEMORY_SCOPE_AGENT);
            } while ((unsigned)(m >> 32) != want);
            h_lds[t & 1][tid] = __uint_as_float((unsigned)m);
        }
        block_sync_lds();   // the ONLY barrier per step -- does NOT drain vmcnt

        // 4-gate partial dot over this thread's 16-k slice (b64, 0-conflict)
        const char* hb = (const char*)(&h_lds[t & 1][0]);
        float p0 = 0.f, p1 = 0.f, p2 = 0.f, p3 = 0.f;
        #pragma unroll
        for (int i = 0; i < 8; ++i) {
            float2 h2 = *(const float2*)(hb + off[i]);
            p0 += w[i*2+0]*h2.x + w[i*2+1]*h2.y;
            p1 += w[16+i*2+0]*h2.x + w[16+i*2+1]*h2.y;
            p2 += w[32+i*2+0]*h2.x + w[32+i*2+1]*h2.y;
            p3 += w[48+i*2+0]*h2.x + w[48+i*2+1]*h2.y;
        }

        // sum across the 16 k-slices: 4 uniform DPP rounds; all lanes get sum
        p0 = dpp_add<0xB1>(p0);  p1 = dpp_add<0xB1>(p1);
        p2 = dpp_add<0xB1>(p2);  p3 = dpp_add<0xB1>(p3);
        p0 = dpp_add<0x4E>(p0);  p1 = dpp_add<0x4E>(p1);
        p2 = dpp_add<0x4E>(p2);  p3 = dpp_add<0x4E>(p3);
        p0 = dpp_add<0x141>(p0); p1 = dpp_add<0x141>(p1);
        p2 = dpp_add<0x141>(p2); p3 = dpp_add<0x141>(p3);
        p0 = dpp_add<0x140>(p0); p1 = dpp_add<0x140>(p1);
        p2 = dpp_add<0x140>(p2); p3 = dpp_add<0x140>(p3);

        // activation lanes read gin from LDS (written by wave 7 at step t-1,
        // ordered by this step's barrier; double-buffered vs wave 7's
        // same-phase write to buffer (t+1)&1)
        if (s >= 14) {
            const float* gl = &gin_lds[t & 1][0];
            float gin0 = gl[j], gin1 = gl[256 + j], gin2 = gl[512 + j], gin3 = gl[768 + j];
            float iv = sigmoidf_(gin0 + p0);
            float fv = sigmoidf_(gin1 + p1);
            float gv = tanh_fast(gin2 + p2);
            float ov = sigmoidf_(gin3 + p3);
            c = fv * c + iv * gv;
            float h = ov * tanh_fast(c);
            if (s == 15) {
                // publish: msg first (critical path), then local LDS
                u64 pck = ((u64)(unsigned)(t + 2) << 32) | (u64)__float_as_uint(h);
                __hip_atomic_store(&msg[(((t + 1) & 1) * 2 + dir) * 256 + j], pck,
                                   __ATOMIC_RELAXED, __HIP_MEMORY_SCOPE_AGENT);
                h_lds[(t + 1) & 1][j] = h;
            } else {
                h_out[(size_t)tf * 512 + dir * HH + j] = h;
            }
        }

        // IO wave: commit gin row t+1 to LDS (loads a full step old -> the
        // compiler's register-dep waitcnt is already satisfied or nearly so)
        // and issue row t+2. These loads now survive the next barrier.
        if (wv == 7) {
            if (t + 1 < T_LEN) {
                float4* gl = (float4*)&gin_lds[(t + 1) & 1][0];
                gl[lio] = q0; gl[lio + 64] = q1; gl[lio + 128] = q2; gl[lio + 192] = q3;
            }
            if (t + 2 < T_LEN) {
                const int tf2 = dir ? (T_LEN - 3 - t) : (t + 2);
                const float4* r = (const float4*)(gates + (size_t)tf2 * 1024);
                q0 = r[lio]; q1 = r[lio + 64]; q2 = r[lio + 128]; q3 = r[lio + 192];
            }
        }
        // ABA-safe (unchanged protocol): producer overwrites buf (t+1)&1 (its
        // tag-t slot) only after this step's poll saw remote tags t+1, which
        // imply every remote block passed its step-(t-1) barrier and thus
        // consumed tag t already. Raw s_barrier preserves poll<barrier<publish
        // program order; poll loads complete (vmcnt-waited in the loop)
        // before the publish store issues.
    }
}

// ---------------------------------------------------------------------------
// Kernel 3: feats[t][k] = dot(h_out[t,:], W_out[k,:]) + b_out[k]  (unchanged)
// ---------------------------------------------------------------------------
__global__ __launch_bounds__(64) void feats_kernel(
    const float* __restrict__ h_out, const float* __restrict__ W_out,
    const float* __restrict__ b_out, float* __restrict__ feats)
{
    const int t = blockIdx.x;
    const int lane = threadIdx.x;
    const int k = lane >> 1, half = lane & 1;
    const float4* hv = (const float4*)(h_out + (size_t)t * 512 + half * 256);
    const float4* wv = (const float4*)(W_out + (size_t)k * 512 + half * 256);
    float p = 0.f;
    #pragma unroll 16
    for (int i = 0; i < 64; ++i) {
        float4 a = hv[i], b = wv[i];
        p += a.x*b.x + a.y*b.y + a.z*b.z + a.w*b.w;
    }
    p += __shfl_xor(p, 1);
    if (half == 0) feats[t * 32 + k] = p + b_out[k];
}

// ---------------------------------------------------------------------------
// Kernel 4: Viterbi (R7 version, proven: cut ~1.85ms vs the shfl-gather
// version). LDS alpha broadcast: ih==0 lanes write 32 alphas (1 ds_write),
// every lane reads its 16 via 4 ds_read_b128 (2 distinct addrs/instr ->
// broadcast, conflict-free). Single wave => in-order LDS pipe, no barrier.
// obs folded AFTER the max (argmax invariant under +obs[j]).
// ---------------------------------------------------------------------------
#define VT_CHUNK 128
__global__ __launch_bounds__(64) void viterbi_kernel(
    const float* __restrict__ feats, const float* __restrict__ trans,
    float* __restrict__ out)
{
    extern __shared__ unsigned char dynls[];
    unsigned char* ixs = dynls;                       // (T-1)*32 = 131040 B
    float* fchunk = (float*)(dynls + 131072);         // VT_CHUNK*32 floats
    __shared__ __align__(16) float alf[32];
    __shared__ float fin[32];

    const int lane = threadIdx.x;
    const int j = lane >> 1, ih = lane & 1;

    float ttr[16];
    #pragma unroll
    for (int q = 0; q < 16; ++q) ttr[q] = trans[(ih * 16 + q) * 32 + j];

    float alpha = 0.f;

    for (int cs = 0; cs < T_LEN; cs += VT_CHUNK) {
        const float4* src = (const float4*)(feats + (size_t)cs * 32);
        float4* dst = (float4*)fchunk;
        #pragma unroll
        for (int i = 0; i < 16; ++i) dst[lane + 64 * i] = src[lane + 64 * i];
        __syncthreads();

        int tbeg = cs;
        if (cs == 0) { alpha = fchunk[j]; tbeg = 1; }

        for (int t = tbeg; t < cs + VT_CHUNK; ++t) {
            if (ih == 0) alf[j] = alpha;   // in-order LDS pipe: safe pre-read
            float obs = fchunk[(t - cs) * 32 + j];
            float4 a0 = *(const float4*)&alf[ih * 16 + 0];
            float4 a1 = *(const float4*)&alf[ih * 16 + 4];
            float4 a2 = *(const float4*)&alf[ih * 16 + 8];
            float4 a3 = *(const float4*)&alf[ih * 16 + 12];

            float v[16]; int ix[16];
            v[0]  = a0.x + ttr[0];  v[1]  = a0.y + ttr[1];
            v[2]  = a0.z + ttr[2];  v[3]  = a0.w + ttr[3];
            v[4]  = a1.x + ttr[4];  v[5]  = a1.y + ttr[5];
            v[6]  = a1.z + ttr[6];  v[7]  = a1.w + ttr[7];
            v[8]  = a2.x + ttr[8];  v[9]  = a2.y + ttr[9];
            v[10] = a2.z + ttr[10]; v[11] = a2.w + ttr[11];
            v[12] = a3.x + ttr[12]; v[13] = a3.y + ttr[13];
            v[14] = a3.z + ttr[14]; v[15] = a3.w + ttr[15];
            #pragma unroll
            for (int q = 0; q < 16; ++q) ix[q] = ih * 16 + q;

            #pragma unroll
            for (int st = 8; st >= 1; st >>= 1)
                #pragma unroll
                for (int q = 0; q < 8; ++q)
                    if (q < st && v[q + st] > v[q]) { v[q] = v[q + st]; ix[q] = ix[q + st]; }
            float best = v[0]; int barg = ix[0];

            float ob = __shfl_xor(best, 1); int oa = __shfl_xor(barg, 1);
            float m0 = ih ? ob : best; int a0i = ih ? oa : barg;
            float m1 = ih ? best : ob; int a1i = ih ? barg : oa;
            float m = m0; int a = a0i;
            if (m1 > m0) { m = m1; a = a1i; }
            if (ih == 0) ixs[(t - 1) * 32 + j] = (unsigned char)a;
            alpha = m + obs;
        }
        __syncthreads();
    }

    if (ih == 0) fin[j] = alpha;
    __syncthreads();

    if (lane == 0) {
        float sc = fin[0]; int cur = 0;
        for (int q = 1; q < 32; ++q)
            if (fin[q] > sc) { sc = fin[q]; cur = q; }
        out[T_LEN] = sc;
        out[T_LEN - 1] = (float)cur;
        for (int t = T_LEN - 2; t >= 0; --t) {
            cur = ixs[t * 32 + cur];
            out[t] = (float)cur;
        }
    }
}

// ---------------------------------------------------------------------------
extern "C" void kernel_launch(void* const* d_in, const int* in_sizes, int n_in,
                              void* d_out, int out_size, void* d_ws, size_t ws_size,
                              hipStream_t stream) {
    const int*   sent  = (const int*)d_in[0];
    const float* embed = (const float*)d_in[1];
    const float* Wih_f = (const float*)d_in[2];
    const float* Whh_f = (const float*)d_in[3];
    const float* bih_f = (const float*)d_in[4];
    const float* bhh_f = (const float*)d_in[5];
    const float* Wih_b = (const float*)d_in[6];
    const float* Whh_b = (const float*)d_in[7];
    const float* bih_b = (const float*)d_in[8];
    const float* bhh_b = (const float*)d_in[9];
    const float* h0    = (const float*)d_in[10];
    const float* c0    = (const float*)d_in[11];
    const float* W_out = (const float*)d_in[12];
    const float* b_out = (const float*)d_in[13];
    const float* trans = (const float*)d_in[14];
    float* out = (float*)d_out;

    float* gates_f = (float*)d_ws;                              // T*1024
    float* gates_b = gates_f + (size_t)T_LEN * 1024;            // T*1024
    float* h_out   = gates_b + (size_t)T_LEN * 1024;            // T*512
    float* feats   = h_out   + (size_t)T_LEN * 512;             // T*32
    u64*   msg     = (u64*)(feats + (size_t)T_LEN * 32);        // 2*2*256

    dim3 gproj(T_LEN / 16, 2);
    proj_kernel<<<gproj, 256, 0, stream>>>(sent, embed,
        Wih_f, bih_f, bhh_f, Wih_b, bih_b, bhh_b, gates_f, gates_b);

    lstm_kernel<<<64, 512, 0, stream>>>(Whh_f, Whh_b, gates_f, gates_b,
                                        h0, c0, h_out, msg);

    feats_kernel<<<T_LEN, 64, 0, stream>>>(h_out, W_out, b_out, feats);

    hipFuncSetAttribute((const void*)viterbi_kernel,
                        hipFuncAttributeMaxDynamicSharedMemorySize, 147456);
    viterbi_kernel<<<1, 64, 147456, stream>>>(feats, trans, out);
}

// Round 9
// 6139.748 us; speedup vs baseline: 1.5764x; 1.5764x over previous
//
#include <hip/hip_runtime.h>
#include <stdint.h>

#define T_LEN 4096
#define E_DIM 256
#define HH 256

typedef unsigned long long u64;

__device__ __forceinline__ float sigmoidf_(float x) {
    // 1/(1+e^-x) with approx rcp (rel err ~1e-7, fine vs 2% score threshold)
    return __builtin_amdgcn_rcpf(1.0f + __expf(-x));
}
// tanh via exp identity; exact saturation at +-1
__device__ __forceinline__ float tanh_fast(float x) {
    float e = __expf(2.0f * x);
    return 1.0f - 2.0f * __builtin_amdgcn_rcpf(e + 1.0f);
}

// DPP-based add of a permuted lane: pure VALU. CTRL: 0xB1 = quad_perm xor1,
// 0x4E = quad_perm xor2, 0x141 = ROW_HALF_MIRROR (l^7), 0x140 = ROW_MIRROR
// (l^15). After the 4-round chain ALL 16 lanes of each 16-row hold the row
// sum (mirrors are valid because values are quad/octet-uniform by then).
template <int CTRL>
__device__ __forceinline__ float dpp_add(float x) {
    int t = __builtin_amdgcn_update_dpp(0, __float_as_int(x), CTRL, 0xF, 0xF, true);
    return x + __int_as_float(t);
}

// ---------------------------------------------------------------------------
// Kernel 1: embedding gather fused with input projection. (unchanged)
// ---------------------------------------------------------------------------
__global__ __launch_bounds__(256) void proj_kernel(
    const int* __restrict__ sent, const float* __restrict__ embed,
    const float* __restrict__ Wih_f, const float* __restrict__ bih_f, const float* __restrict__ bhh_f,
    const float* __restrict__ Wih_b, const float* __restrict__ bih_b, const float* __restrict__ bhh_b,
    float* __restrict__ gates_f, float* __restrict__ gates_b)
{
    __shared__ float4 xt[16][64];   // 16 timesteps x 256 floats
    const int tid = threadIdx.x;
    const int dir = blockIdx.y;
    const int t0  = blockIdx.x * 16;

    const float* Wih = dir ? Wih_b : Wih_f;
    const float* bih = dir ? bih_b : bih_f;
    const float* bhh = dir ? bhh_b : bhh_f;
    float* gates     = dir ? gates_b : gates_f;

    {   // gather 16 embedding rows into LDS (coalesced 16B/lane)
        int row = tid >> 4;
        int c   = tid & 15;
        const float4* src = (const float4*)(embed + (size_t)sent[t0 + row] * E_DIM);
        xt[row][c]      = src[c];
        xt[row][c + 16] = src[c + 16];
        xt[row][c + 32] = src[c + 32];
        xt[row][c + 48] = src[c + 48];
    }
    __syncthreads();

    float acc[4][16];
    #pragma unroll
    for (int ri = 0; ri < 4; ++ri)
        #pragma unroll
        for (int tt = 0; tt < 16; ++tt) acc[ri][tt] = 0.f;

    const float4* wrow0 = (const float4*)(Wih + (size_t)(0 * 256 + tid) * 256);
    const float4* wrow1 = (const float4*)(Wih + (size_t)(1 * 256 + tid) * 256);
    const float4* wrow2 = (const float4*)(Wih + (size_t)(2 * 256 + tid) * 256);
    const float4* wrow3 = (const float4*)(Wih + (size_t)(3 * 256 + tid) * 256);

    for (int k4 = 0; k4 < 64; ++k4) {
        float4 xv[16];
        #pragma unroll
        for (int tt = 0; tt < 16; ++tt) xv[tt] = xt[tt][k4];
        float4 w0 = wrow0[k4], w1 = wrow1[k4], w2 = wrow2[k4], w3 = wrow3[k4];
        #pragma unroll
        for (int tt = 0; tt < 16; ++tt) {
            acc[0][tt] += w0.x*xv[tt].x + w0.y*xv[tt].y + w0.z*xv[tt].z + w0.w*xv[tt].w;
            acc[1][tt] += w1.x*xv[tt].x + w1.y*xv[tt].y + w1.z*xv[tt].z + w1.w*xv[tt].w;
            acc[2][tt] += w2.x*xv[tt].x + w2.y*xv[tt].y + w2.z*xv[tt].z + w2.w*xv[tt].w;
            acc[3][tt] += w3.x*xv[tt].x + w3.y*xv[tt].y + w3.z*xv[tt].z + w3.w*xv[tt].w;
        }
    }

    #pragma unroll
    for (int ri = 0; ri < 4; ++ri) {
        int r = ri * 256 + tid;
        float b = bih[r] + bhh[r];
        #pragma unroll
        for (int tt = 0; tt < 16; ++tt)
            gates[(size_t)(t0 + tt) * 1024 + r] = acc[ri][tt] + b;
    }
}

// ---------------------------------------------------------------------------
// Kernel 2: BiLSTM recurrence. R13 = R6 verbatim (best measured: 4170us,
// 2443cy/step) with ONE change: the next-step gin prefetch is issued AFTER
// the barrier instead of before the poll.
// Mechanism (R6..R12 evidence): every wave has s==0 lanes with in-flight
// HBM gin loads; the poll's vmcnt(0) (waves 0-3) and __syncthreads' implicit
// vmcnt(0) drain (waves 4-7) wait on them. R6 issued the loads immediately
// before the poll -> full ~900cy exposed. Issuing after the barrier puts
// dot+DPP+activation+publish (~600-800cy) between issue and the next drain
// point -> exposed wait ~100-300cy. Same depth-1 pipeline, same consumers,
// no role/wave/barrier changes (R8/R11/R12's failure modes absent).
// Everything else R6-proven: 8 blocks/dir x 32 hidden, thread (j=tid>>4,
// s=tid&15), agent-atomic 1-slot-per-poller msg protocol, LDS h staging,
// 0-conflict b64 rotation f(s)=(s+(s>>3))&7, AGPR-pinned w, DPP reduce.
// ---------------------------------------------------------------------------
__global__ __launch_bounds__(512, 1) void lstm_kernel(
    const float* __restrict__ Whh_f, const float* __restrict__ Whh_b,
    const float* __restrict__ gates_f, const float* __restrict__ gates_b,
    const float* __restrict__ h0, const float* __restrict__ c0,
    float* __restrict__ h_out, u64* __restrict__ msg)
{
    const int xcd  = blockIdx.x & 7;
    const int slot = blockIdx.x >> 3;
    if (xcd > 1) return;               // filler blocks exit
    const int dir = xcd;
    const int g   = slot;              // 0..7, owns hidden [g*32, g*32+32)

    const int tid = threadIdx.x;
    const int jl  = tid >> 4;          // local hidden 0..31
    const int s   = tid & 15;          // k-slice 0..15 (16 floats each)
    const int j   = g * 32 + jl;       // global hidden index
    const int f   = (s + (s >> 3)) & 7;  // bank de-correlation rotation

    const float* Whh   = dir ? Whh_b : Whh_f;
    const float* gates = dir ? gates_b : gates_f;

    // w[gg*16 + i*2 + c] = Whh[gg*256+j][s*16 + ((3i+f)&7)*2 + c]
    // (stored in ds-visit order so the dot loop reads w linearly)
    float w[64];
    #pragma unroll
    for (int gg = 0; gg < 4; ++gg) {
        const float2* row2 = (const float2*)(Whh + (size_t)(gg * 256 + j) * 256 + s * 16);
        #pragma unroll
        for (int i = 0; i < 8; ++i) {
            float2 v = row2[(3 * i + f) & 7];
            w[gg * 16 + i * 2 + 0] = v.x;
            w[gg * 16 + i * 2 + 1] = v.y;
        }
    }
    // AGPR pin: forces w into the accumulator file; VALU reads a-regs as
    // FMA sources in place (gfx90a+), so no per-step accvgpr_read fills and
    // no rematerialization-from-memory.
    #pragma unroll
    for (int k = 0; k < 64; ++k)
        asm volatile("" : "+a"(w[k]));

    // per-i LDS byte offsets (t-invariant; 8 VGPRs, static-indexed)
    int off[8];
    #pragma unroll
    for (int i = 0; i < 8; ++i)
        off[i] = s * 64 + ((3 * i + f) & 7) * 8;

    __shared__ __align__(16) float h_lds[2][256];

    float c = 0.f;
    if (tid < 32) {
        int j0 = g * 32 + tid;
        float h = h0[dir * HH + j0];
        h_lds[0][j0] = h;
        u64 p = ((u64)1u << 32) | (u64)__float_as_uint(h);
        __hip_atomic_store(&msg[(0 * 2 + dir) * 256 + j0], p,
                           __ATOMIC_RELAXED, __HIP_MEMORY_SCOPE_AGENT);
    }
    if (s == 0) c = c0[dir * HH + j];

    // gin for step 0, loaded pre-loop (plenty of slack before first use)
    float gin0 = 0.f, gin1 = 0.f, gin2 = 0.f, gin3 = 0.f;
    if (s == 0) {
        const int tf0 = dir ? (T_LEN - 1) : 0;
        const float* gp = gates + (size_t)tf0 * 1024 + j;
        gin0 = gp[0]; gin1 = gp[256]; gin2 = gp[512]; gin3 = gp[768];
    }

    for (int t = 0; t < T_LEN; ++t) {
        const int tf = dir ? (T_LEN - 1 - t) : t;

        // poll the 224 remote h values (own 32 written locally last step).
        // gin loads in flight here were issued ~600-800cy ago (post-barrier
        // of step t-1) -> the vmcnt(0) inside this loop waits only their
        // residual latency, not the full ~900cy (the R13 change).
        if (tid < 256 && (tid >> 5) != g) {
            u64* sp = &msg[((t & 1) * 2 + dir) * 256 + tid];
            const unsigned want = (unsigned)(t + 1);
            u64 m;
            do {
                m = __hip_atomic_load(sp, __ATOMIC_RELAXED, __HIP_MEMORY_SCOPE_AGENT);
            } while ((unsigned)(m >> 32) != want);
            h_lds[t & 1][tid] = __uint_as_float((unsigned)m);
        }
        __syncthreads();   // the ONLY barrier per step

        // prefetch NEXT step's gate inputs -- issued AFTER the barrier (R13):
        // the next drain point (step t+1's poll / barrier) is a full
        // dot+DPP+activation+publish away, hiding most of the HBM latency.
        float ng0 = 0.f, ng1 = 0.f, ng2 = 0.f, ng3 = 0.f;
        if (s == 0 && t + 1 < T_LEN) {
            const int tfn = dir ? (T_LEN - 2 - t) : (t + 1);
            const float* gp = gates + (size_t)tfn * 1024 + j;
            ng0 = gp[0]; ng1 = gp[256]; ng2 = gp[512]; ng3 = gp[768];
        }

        // 4-gate partial dot over this thread's 16-k slice (b64, 0-conflict)
        const char* hb = (const char*)(&h_lds[t & 1][0]);
        float p0 = 0.f, p1 = 0.f, p2 = 0.f, p3 = 0.f;
        #pragma unroll
        for (int i = 0; i < 8; ++i) {
            float2 h2 = *(const float2*)(hb + off[i]);
            p0 += w[i*2+0]*h2.x + w[i*2+1]*h2.y;
            p1 += w[16+i*2+0]*h2.x + w[16+i*2+1]*h2.y;
            p2 += w[32+i*2+0]*h2.x + w[32+i*2+1]*h2.y;
            p3 += w[48+i*2+0]*h2.x + w[48+i*2+1]*h2.y;
        }

        // sum across the 16 k-slices: 4 uniform DPP rounds, all-VALU
        p0 = dpp_add<0xB1>(p0);  p1 = dpp_add<0xB1>(p1);
        p2 = dpp_add<0xB1>(p2);  p3 = dpp_add<0xB1>(p3);
        p0 = dpp_add<0x4E>(p0);  p1 = dpp_add<0x4E>(p1);
        p2 = dpp_add<0x4E>(p2);  p3 = dpp_add<0x4E>(p3);
        p0 = dpp_add<0x141>(p0); p1 = dpp_add<0x141>(p1);
        p2 = dpp_add<0x141>(p2); p3 = dpp_add<0x141>(p3);
        p0 = dpp_add<0x140>(p0); p1 = dpp_add<0x140>(p1);
        p2 = dpp_add<0x140>(p2); p3 = dpp_add<0x140>(p3);

        if (s == 0) {
            float iv = sigmoidf_(gin0 + p0);
            float fv = sigmoidf_(gin1 + p1);
            float gv = tanh_fast(gin2 + p2);
            float ov = sigmoidf_(gin3 + p3);
            c = fv * c + iv * gv;
            float h = ov * tanh_fast(c);
            // publish: msg first (critical path), then local LDS, then h_out
            u64 pck = ((u64)(unsigned)(t + 2) << 32) | (u64)__float_as_uint(h);
            __hip_atomic_store(&msg[(((t + 1) & 1) * 2 + dir) * 256 + j], pck,
                               __ATOMIC_RELAXED, __HIP_MEMORY_SCOPE_AGENT);
            h_lds[(t + 1) & 1][j] = h;
            h_out[(size_t)tf * 512 + dir * HH + j] = h;
        }
        gin0 = ng0; gin1 = ng1; gin2 = ng2; gin3 = ng3;
        // ABA-safe (unchanged protocol): producer overwrites buf (t+1)&1 (its
        // tag-t slot) only after this step's poll saw remote tags t+1, which
        // imply every remote block passed its step-(t-1) barrier and thus
        // consumed tag t already.
    }
}

// ---------------------------------------------------------------------------
// Kernel 3: feats[t][k] = dot(h_out[t,:], W_out[k,:]) + b_out[k]  (unchanged)
// ---------------------------------------------------------------------------
__global__ __launch_bounds__(64) void feats_kernel(
    const float* __restrict__ h_out, const float* __restrict__ W_out,
    const float* __restrict__ b_out, float* __restrict__ feats)
{
    const int t = blockIdx.x;
    const int lane = threadIdx.x;
    const int k = lane >> 1, half = lane & 1;
    const float4* hv = (const float4*)(h_out + (size_t)t * 512 + half * 256);
    const float4* wv = (const float4*)(W_out + (size_t)k * 512 + half * 256);
    float p = 0.f;
    #pragma unroll 16
    for (int i = 0; i < 64; ++i) {
        float4 a = hv[i], b = wv[i];
        p += a.x*b.x + a.y*b.y + a.z*b.z + a.w*b.w;
    }
    p += __shfl_xor(p, 1);
    if (half == 0) feats[t * 32 + k] = p + b_out[k];
}

// ---------------------------------------------------------------------------
// Kernel 4: Viterbi (R7 version, proven: cut ~1.85ms vs the shfl-gather
// version). LDS alpha broadcast: ih==0 lanes write 32 alphas (1 ds_write),
// every lane reads its 16 via 4 ds_read_b128 (2 distinct addrs/instr ->
// broadcast, conflict-free). Single wave => in-order LDS pipe, no barrier.
// obs folded AFTER the max (argmax invariant under +obs[j]).
// ---------------------------------------------------------------------------
#define VT_CHUNK 128
__global__ __launch_bounds__(64) void viterbi_kernel(
    const float* __restrict__ feats, const float* __restrict__ trans,
    float* __restrict__ out)
{
    extern __shared__ unsigned char dynls[];
    unsigned char* ixs = dynls;                       // (T-1)*32 = 131040 B
    float* fchunk = (float*)(dynls + 131072);         // VT_CHUNK*32 floats
    __shared__ __align__(16) float alf[32];
    __shared__ float fin[32];

    const int lane = threadIdx.x;
    const int j = lane >> 1, ih = lane & 1;

    float ttr[16];
    #pragma unroll
    for (int q = 0; q < 16; ++q) ttr[q] = trans[(ih * 16 + q) * 32 + j];

    float alpha = 0.f;

    for (int cs = 0; cs < T_LEN; cs += VT_CHUNK) {
        const float4* src = (const float4*)(feats + (size_t)cs * 32);
        float4* dst = (float4*)fchunk;
        #pragma unroll
        for (int i = 0; i < 16; ++i) dst[lane + 64 * i] = src[lane + 64 * i];
        __syncthreads();

        int tbeg = cs;
        if (cs == 0) { alpha = fchunk[j]; tbeg = 1; }

        for (int t = tbeg; t < cs + VT_CHUNK; ++t) {
            if (ih == 0) alf[j] = alpha;   // in-order LDS pipe: safe pre-read
            float obs = fchunk[(t - cs) * 32 + j];
            float4 a0 = *(const float4*)&alf[ih * 16 + 0];
            float4 a1 = *(const float4*)&alf[ih * 16 + 4];
            float4 a2 = *(const float4*)&alf[ih * 16 + 8];
            float4 a3 = *(const float4*)&alf[ih * 16 + 12];

            float v[16]; int ix[16];
            v[0]  = a0.x + ttr[0];  v[1]  = a0.y + ttr[1];
            v[2]  = a0.z + ttr[2];  v[3]  = a0.w + ttr[3];
            v[4]  = a1.x + ttr[4];  v[5]  = a1.y + ttr[5];
            v[6]  = a1.z + ttr[6];  v[7]  = a1.w + ttr[7];
            v[8]  = a2.x + ttr[8];  v[9]  = a2.y + ttr[9];
            v[10] = a2.z + ttr[10]; v[11] = a2.w + ttr[11];
            v[12] = a3.x + ttr[12]; v[13] = a3.y + ttr[13];
            v[14] = a3.z + ttr[14]; v[15] = a3.w + ttr[15];
            #pragma unroll
            for (int q = 0; q < 16; ++q) ix[q] = ih * 16 + q;

            #pragma unroll
            for (int st = 8; st >= 1; st >>= 1)
                #pragma unroll
                for (int q = 0; q < 8; ++q)
                    if (q < st && v[q + st] > v[q]) { v[q] = v[q + st]; ix[q] = ix[q + st]; }
            float best = v[0]; int barg = ix[0];

            float ob = __shfl_xor(best, 1); int oa = __shfl_xor(barg, 1);
            float m0 = ih ? ob : best; int a0i = ih ? oa : barg;
            float m1 = ih ? best : ob; int a1i = ih ? barg : oa;
            float m = m0; int a = a0i;
            if (m1 > m0) { m = m1; a = a1i; }
            if (ih == 0) ixs[(t - 1) * 32 + j] = (unsigned char)a;
            alpha = m + obs;
        }
        __syncthreads();
    }

    if (ih == 0) fin[j] = alpha;
    __syncthreads();

    if (lane == 0) {
        float sc = fin[0]; int cur = 0;
        for (int q = 1; q < 32; ++q)
            if (fin[q] > sc) { sc = fin[q]; cur = q; }
        out[T_LEN] = sc;
        out[T_LEN - 1] = (float)cur;
        for (int t = T_LEN - 2; t >= 0; --t) {
            cur = ixs[t * 32 + cur];
            out[t] = (float)cur;
        }
    }
}

// ---------------------------------------------------------------------------
extern "C" void kernel_launch(void* const* d_in, const int* in_sizes, int n_in,
                              void* d_out, int out_size, void* d_ws, size_t ws_size,
                              hipStream_t stream) {
    const int*   sent  = (const int*)d_in[0];
    const float* embed = (const float*)d_in[1];
    const float* Wih_f = (const float*)d_in[2];
    const float* Whh_f = (const float*)d_in[3];
    const float* bih_f = (const float*)d_in[4];
    const float* bhh_f = (const float*)d_in[5];
    const float* Wih_b = (const float*)d_in[6];
    const float* Whh_b = (const float*)d_in[7];
    const float* bih_b = (const float*)d_in[8];
    const float* bhh_b = (const float*)d_in[9];
    const float* h0    = (const float*)d_in[10];
    const float* c0    = (const float*)d_in[11];
    const float* W_out = (const float*)d_in[12];
    const float* b_out = (const float*)d_in[13];
    const float* trans = (const float*)d_in[14];
    float* out = (float*)d_out;

    float* gates_f = (float*)d_ws;                              // T*1024
    float* gates_b = gates_f + (size_t)T_LEN * 1024;            // T*1024
    float* h_out   = gates_b + (size_t)T_LEN * 1024;            // T*512
    float* feats   = h_out   + (size_t)T_LEN * 512;             // T*32
    u64*   msg     = (u64*)(feats + (size_t)T_LEN * 32);        // 2*2*256

    dim3 gproj(T_LEN / 16, 2);
    proj_kernel<<<gproj, 256, 0, stream>>>(sent, embed,
        Wih_f, bih_f, bhh_f, Wih_b, bih_b, bhh_b, gates_f, gates_b);

    lstm_kernel<<<64, 512, 0, stream>>>(Whh_f, Whh_b, gates_f, gates_b,
                                        h0, c0, h_out, msg);

    feats_kernel<<<T_LEN, 64, 0, stream>>>(h_out, W_out, b_out, feats);

    hipFuncSetAttribute((const void*)viterbi_kernel,
                        hipFuncAttributeMaxDynamicSharedMemorySize, 147456);
    viterbi_kernel<<<1, 64, 147456, stream>>>(feats, trans, out);
}